// Round 5
// baseline (123.726 us; speedup 1.0000x reference)
//
#include <hip/hip_runtime.h>
#include <math.h>

#define NQ   12
#define NL   4
#define GBLK 256
#define QBLK 512
#define S1OFF 8192   // sample-1 state offset in __fp16 units (16 KB)

typedef float v4f  __attribute__((ext_vector_type(4)));
typedef __fp16 v8h __attribute__((ext_vector_type(8)));

// Inverse CNOT-ring map (apply CNOTs in forward order). GF(2)-linear.
__device__ __forceinline__ constexpr int sigma_inv_c(int i) {
    int j = i;
    for (int c = 0; c < NQ; ++c) {
        int t = (c + 1) % NQ;
        int cb = (j >> (NQ - 1 - c)) & 1;
        j ^= cb << (NQ - 1 - t);
    }
    return j;
}

// State buffer: amp (col CC(8b), row r(4b)) as interleaved (re,im) f16 pair.
// 16B line = 4 amps: line = CC*4 + (r>>2). Line swizzle keeps both the
// fragment reads and column writes <=2-way bank conflicts.
__device__ __forceinline__ constexpr int lswz(int l) {
    return l ^ (((l >> 3) ^ (l >> 7)) & 7);
}

__device__ __forceinline__ unsigned pk2(float a, float b) {
    return __builtin_bit_cast(unsigned, __builtin_amdgcn_cvt_pkrtz(a, b));
}

// ---- pre-kernel: fused gates -> 12 U16 matrices -> f16 B-fragments in d_ws ----
__device__ __forceinline__ int fslot(int k, int n) {
    return ((k >> 3) * 16 + n) * 8 + (k & 7);
}

// One block per matrix (12 blocks): shortens the serial pre-kernel bubble.
__global__ __launch_bounds__(GBLK) void gate_kernel(
    const float* __restrict__ qw, __fp16* __restrict__ gout)
{
    __shared__ float G[NQ][8];
    const int t = threadIdx.x;
    const int mat = blockIdx.x;               // 0..11
    const int layer = mat / 3, ph = mat - 3 * layer;
    if (t < NQ) {
        const int p = layer * 3 * NQ + 3 * t;
        float t1 = qw[p], t2 = qw[p + 1], t3 = qw[p + 2];
        float a, b, c, d, gr, h;
        sincosf(0.5f * t1, &b, &a);   // RX
        sincosf(0.5f * t2, &d, &c);   // RY
        sincosf(0.5f * t3, &h, &gr);  // RZ
        float m00r =  c * a, m00i =  d * b;
        float m01r = -d * a, m01i = -c * b;
        float m10r =  d * a, m10i = -c * b;
        float m11r =  c * a, m11i = -d * b;
        float* g = G[t];
        g[0] = gr * m00r + h * m00i;  g[1] = gr * m00i - h * m00r;
        g[2] = gr * m01r + h * m01i;  g[3] = gr * m01i - h * m01r;
        g[4] = gr * m10r - h * m10i;  g[5] = gr * m10i + h * m10r;
        g[6] = gr * m11r - h * m11i;  g[7] = gr * m11i + h * m11r;
    }
    __syncthreads();
    const int n = t & 15, r = t >> 4;
    const int wbase = (ph == 0) ? 8 : (ph == 1) ? 4 : 0;
    float cr = 1.f, ci = 0.f;
    #pragma unroll
    for (int b = 0; b < 4; ++b) {         // bit (3-b) of row <-> wire wbase+b
        const float* g = G[wbase + b];
        const int rb = (r >> (3 - b)) & 1, nb = (n >> (3 - b)) & 1;
        const float er = g[(nb * 2 + rb) * 2], ei = g[(nb * 2 + rb) * 2 + 1];
        const float xr = cr * er - ci * ei, xi = cr * ei + ci * er;
        cr = xr; ci = xi;
    }
    __fp16* b1 = gout + (mat * 2 + 0) * 512;
    __fp16* b2 = gout + (mat * 2 + 1) * 512;
    b1[fslot(2 * r, n)]     = (__fp16)cr;
    b1[fslot(2 * r + 1, n)] = (__fp16)(-ci);
    b2[fslot(2 * r, n)]     = (__fp16)ci;
    b2[fslot(2 * r + 1, n)] = (__fp16)cr;
}

// q-split: wave W covers q in {2*qh, 2*qh+1} (qh = W>>2, wv = W&3).
// Same container algebra as the 4-wave version; per-wave regs halve.
#define READ_FRAGS(AF, SRC)                                                 \
    _Pragma("unroll")                                                       \
    for (int j = 0; j < 2; ++j)                                             \
        AF[j] = __builtin_bit_cast(v8h, *(const uint4*)&sh[(SRC) +          \
                    lswz((((wv) << 6) | ((2 * qh + j) << 4) | nn) * 4 + g) * 8]);

#define BLOAD(MAT)                                                          \
    const v8h b1 = gf[((MAT) * 2 + 0) * 64 + lane];                         \
    const v8h b2 = gf[((MAT) * 2 + 1) * 64 + lane];

#define MFMA_ONE(AF)                                                        \
    _Pragma("unroll")                                                       \
    for (int j = 0; j < 2; ++j) {                                           \
        d1[j] = __builtin_amdgcn_mfma_f32_16x16x32_f16(AF[j], b1, zf, 0, 0, 0); \
        d2[j] = __builtin_amdgcn_mfma_f32_16x16x32_f16(AF[j], b2, zf, 0, 0, 0); \
    }

// Keep the two samples' compute regions from being cross-pipelined
// (R2 lesson: interleaving doubles live accumulators -> VGPR cliff).
#define SCHB __builtin_amdgcn_sched_barrier(0);

#define WRITE_COLS(DST)                                                     \
    _Pragma("unroll")                                                       \
    for (int j = 0; j < 2; ++j) {                                           \
        const int CCn = (nn << 4) | (wv << 2) | (2 * qh + j);               \
        *(uint4*)&sh[(DST) + lswz(CCn * 4 + g) * 8] =                       \
            make_uint4(pk2(d1[j].x, d2[j].x), pk2(d1[j].y, d2[j].y),        \
                       pk2(d1[j].z, d2[j].z), pk2(d1[j].w, d2[j].w));       \
    }

// sq0/sq1 = sigma_inv(q<<4) pre-selected per wave (compile-time folded).
#define WRITE_SIGMA(DST)                                                    \
    _Pragma("unroll")                                                       \
    for (int j = 0; j < 2; ++j) {                                           \
        const int iq = ifix ^ (j ? sq1 : sq0);                              \
        _Pragma("unroll")                                                   \
        for (int rg = 0; rg < 4; ++rg) {                                    \
            const int ii = iq ^ sigma_inv_c(rg);                            \
            *(unsigned*)&sh[(DST) + lswz(ii >> 2) * 8 + (ii & 3) * 2] =     \
                pk2(d1[j][rg], d2[j][rg]);                                  \
        }                                                                   \
    }

// Per-sample epilogue with q-split: 8-pt WHT over (j=q0, rg); the q1=qh
// character enters as a sign; summing the two wave-halves through `red`
// reconstructs the full 16-pt WHT (the sum splits linearly over q).
// Lane-reduce only 4 stages (xor 1..8); 4 writer lanes per wave.
#define WHT_EPI(OFF)                                                        \
    { float p8[8];                                                          \
      _Pragma("unroll")                                                     \
      for (int j = 0; j < 2; ++j)                                           \
          _Pragma("unroll")                                                 \
          for (int rg = 0; rg < 4; ++rg)                                    \
              p8[j * 4 + rg] = d1[j][rg] * d1[j][rg] + d2[j][rg] * d2[j][rg]; \
      _Pragma("unroll")                                                     \
      for (int st = 1; st < 8; st <<= 1) {                                  \
          _Pragma("unroll")                                                 \
          for (int i = 0; i < 8; ++i) {                                     \
              if (!(i & st)) {                                              \
                  const float a = p8[i], b = p8[i ^ st];                    \
                  p8[i] = a + b; p8[i ^ st] = a - b;                        \
              }                                                             \
          }                                                                 \
      }                                                                     \
      float vals[NQ];                                                       \
      _Pragma("unroll")                                                     \
      for (int w = 0; w < NQ; ++w) {                                        \
          const int sb = 11 - w;                                            \
          const int f3 = (sigma_inv_c(0x20) >> sb) & 1;                     \
          const int f2 = (sigma_inv_c(0x10) >> sb) & 1;                     \
          const int f1 = (sigma_inv_c(2)    >> sb) & 1;                     \
          const int f0 = (sigma_inv_c(1)    >> sb) & 1;                     \
          const float v = p8[f2 * 4 + f1 * 2 + f0];                         \
          const int sgn = ((ifix >> sb) & 1) ^ (f3 & qh);                   \
          vals[w] = sgn ? -v : v;                                           \
      }                                                                     \
      _Pragma("unroll")                                                     \
      for (int m = 1; m <= 8; m <<= 1) {                                    \
          _Pragma("unroll")                                                 \
          for (int w = 0; w < NQ; ++w) vals[w] += __shfl_xor(vals[w], m);   \
      }                                                                     \
      if ((lane & 15) == 0) {                                               \
          _Pragma("unroll")                                                 \
          for (int w = 0; w < NQ; ++w)                                      \
              red[(OFF) + W * 48 + (lane >> 4) * 12 + w] = vals[w];         \
      } }

__global__ __launch_bounds__(QBLK, 8) void qsim_kernel(
    const float* __restrict__ x,      // (B, 12)
    const __fp16* __restrict__ gates, // 12 x (B1,B2) f16 fragment tables (d_ws)
    const float* __restrict__ dw,     // (12, 12)
    const float* __restrict__ db,     // (12,)
    float* __restrict__ out,          // (B, 12)
    int batch)
{
    // Two samples per block (2x16KB in-place buffers), 8 waves (q-split):
    // per-wave regs ~52-58 -> 8 waves/SIMD -> 4 blocks/CU (128KB LDS).
    __shared__ __align__(16) __fp16 sh[16384];
    float* xv    = (float*)sh;        // [0..23]
    float* enc_c = (float*)sh + 32;   // [32..55]
    float* enc_s = (float*)sh + 64;   // [64..87]
    float* red   = (float*)sh;

    const int tid  = threadIdx.x;
    const int lane = tid & 63;
    const int W    = tid >> 6;        // wave 0..7
    const int wv   = W & 3;           // CC wave field (wires 0-1)
    const int qh   = W >> 2;          // q-half selector (q1 bit)
    const int s0   = 2 * blockIdx.x;
    int s1 = s0 + 1; if (s1 >= batch) s1 = batch - 1;   // odd-batch clamp
    const int nn = lane & 15, g = lane >> 4;
    const v8h* gf = (const v8h*)gates;
    const v4f zf = {0.f, 0.f, 0.f, 0.f};

    if (tid < 2 * NQ) {
        const int smp = tid / NQ, j = tid - smp * NQ;
        xv[tid] = x[(smp ? s1 : s0) * NQ + j];
    }
    __syncthreads();
    if (tid < 2 * NQ) {
        const int base = (tid / NQ) * NQ;
        float ss = 0.f;
        #pragma unroll
        for (int j = 0; j < NQ; ++j) ss += xv[base + j] * xv[base + j];
        float inv = rsqrtf(fmaxf(ss, 1e-12f));
        float mx = 0.f;
        #pragma unroll
        for (int j = 0; j < NQ; ++j) mx = fmaxf(mx, fabsf(xv[base + j] * inv));
        float ang = 3.14159265358979323846f * (xv[tid] * inv) / (mx + 1e-8f);
        float cc, sn;
        sincosf(0.5f * ang, &sn, &cc);
        enc_c[tid] = cc; enc_s[tid] = sn;
    }
    __syncthreads();

    // ---- product-state init as phase-A A-fragments (interleaved re/im) ----
    v8h af0[2], af1[2];
    #define PICK(SMP, WW, B) ((B) ? enc_s[(SMP) * NQ + (WW)] : enc_c[(SMP) * NQ + (WW)])
    #define INIT_AF(AF, SMP)                                                \
    {   float R4[4];                                                        \
        _Pragma("unroll")                                                   \
        for (int t = 0; t < 4; ++t) {                                       \
            const int r = 4 * g + t;                                        \
            R4[t] = PICK(SMP, 8, (r >> 3) & 1) * PICK(SMP, 9, (r >> 2) & 1) \
                  * PICK(SMP, 10, (r >> 1) & 1) * PICK(SMP, 11, r & 1);     \
        }                                                                   \
        const float Pfix = PICK(SMP, 0, (wv >> 1) & 1) * PICK(SMP, 1, wv & 1) \
                         * PICK(SMP, 4, (nn >> 3) & 1) * PICK(SMP, 5, (nn >> 2) & 1) \
                         * PICK(SMP, 6, (nn >> 1) & 1) * PICK(SMP, 7, nn & 1); \
        _Pragma("unroll")                                                   \
        for (int j = 0; j < 2; ++j) {                                       \
            const float Pq = Pfix * PICK(SMP, 2, qh) * PICK(SMP, 3, j);     \
            _Pragma("unroll")                                               \
            for (int t = 0; t < 4; ++t) {                                   \
                AF[j][2 * t]     = (__fp16)(Pq * R4[t]);                    \
                AF[j][2 * t + 1] = (__fp16)0.f;                             \
            }                                                               \
        }                                                                   \
    }
    INIT_AF(af0, 0)
    INIT_AF(af1, 1)
    #undef PICK
    __syncthreads();   // enc reads done before state buffers are written

    const int ifix = sigma_inv_c((nn << 8) | (wv << 6) | (g << 2));
    const int sq0 = qh ? sigma_inv_c(0x20) : 0;
    const int sq1 = qh ? sigma_inv_c(0x30) : sigma_inv_c(0x10);

    v4f d1[2], d2[2];
    #pragma unroll 1
    for (int l = 0; l < NL; ++l) {
        if (l > 0) {
            READ_FRAGS(af0, 0)
            READ_FRAGS(af1, S1OFF)
            __syncthreads();              // all reads landed before writes
        }
        { BLOAD(l * 3 + 0)                // wires 8..11
          MFMA_ONE(af0) WRITE_COLS(0)
          SCHB
          MFMA_ONE(af1) WRITE_COLS(S1OFF) }
        __syncthreads();

        READ_FRAGS(af0, 0)
        READ_FRAGS(af1, S1OFF)
        __syncthreads();
        { BLOAD(l * 3 + 1)                // wires 4..7
          MFMA_ONE(af0) WRITE_COLS(0)
          SCHB
          MFMA_ONE(af1) WRITE_COLS(S1OFF) }
        __syncthreads();

        READ_FRAGS(af0, 0)
        READ_FRAGS(af1, S1OFF)
        __syncthreads();                  // reads drained (sh dead if last)
        if (l < NL - 1) {
            { BLOAD(l * 3 + 2)            // wires 0..3 + CNOT ring fold
              MFMA_ONE(af0) WRITE_SIGMA(0)
              SCHB
              MFMA_ONE(af1) WRITE_SIGMA(S1OFF) }
            __syncthreads();
        } else {
            { BLOAD(l * 3 + 2)            // final: straight into epilogue
              MFMA_ONE(af0)
              WHT_EPI(0)
              SCHB
              MFMA_ONE(af1)
              WHT_EPI(384) }
        }
    }

    __syncthreads();   // all red partials written
    if (tid < 2 * NQ) {
        const int smp = tid / NQ, w = tid - smp * NQ;
        float acc = 0.f;
        #pragma unroll
        for (int k = 0; k < 32; ++k) acc += red[smp * 384 + k * 12 + w];
        red[768 + tid] = acc;
    }
    __syncthreads();
    if (tid < 2 * NQ) {
        const int smp = tid / NQ, o = tid - smp * NQ;
        const float* rv = red + 768 + smp * NQ;
        float v = db[o];
        #pragma unroll
        for (int w = 0; w < NQ; ++w) v += rv[w] * dw[w * NQ + o];
        out[(smp ? s1 : s0) * NQ + o] = tanhf(v);
    }
}

extern "C" void kernel_launch(void* const* d_in, const int* in_sizes, int n_in,
                              void* d_out, int out_size, void* d_ws, size_t ws_size,
                              hipStream_t stream) {
    const float* x  = (const float*)d_in[0];
    const float* qw = (const float*)d_in[1];
    const float* dw = (const float*)d_in[2];
    const float* db = (const float*)d_in[3];
    float* out = (float*)d_out;
    __fp16* gates = (__fp16*)d_ws;          // 12 x 2 x 512 f16 = 24576 B
    int batch = in_sizes[0] / NQ;
    int nblk = (batch + 1) / 2;
    gate_kernel<<<12, GBLK, 0, stream>>>(qw, gates);
    qsim_kernel<<<nblk, QBLK, 0, stream>>>(x, gates, dw, db, out, batch);
}

// Round 6
// 116.766 us; speedup vs baseline: 1.0596x; 1.0596x over previous
//
#include <hip/hip_runtime.h>
#include <math.h>

#define NQ   12
#define NL   4
#define GBLK 256
#define QBLK 512
#define S1OFF 8192   // sample-1 state offset in __fp16 units (16 KB)

typedef float v4f  __attribute__((ext_vector_type(4)));
typedef __fp16 v8h __attribute__((ext_vector_type(8)));

// Inverse CNOT-ring map (apply CNOTs in forward order). GF(2)-linear.
__device__ __forceinline__ constexpr int sigma_inv_c(int i) {
    int j = i;
    for (int c = 0; c < NQ; ++c) {
        int t = (c + 1) % NQ;
        int cb = (j >> (NQ - 1 - c)) & 1;
        j ^= cb << (NQ - 1 - t);
    }
    return j;
}

// State buffer: amp (col CC(8b), row r(4b)) as interleaved (re,im) f16 pair.
// 16B line = 4 amps: line = CC*4 + (r>>2). Line swizzle keeps both the
// fragment reads and column writes <=2-way bank conflicts.
__device__ __forceinline__ constexpr int lswz(int l) {
    return l ^ (((l >> 3) ^ (l >> 7)) & 7);
}

__device__ __forceinline__ unsigned pk2(float a, float b) {
    return __builtin_bit_cast(unsigned, __builtin_amdgcn_cvt_pkrtz(a, b));
}

// ---- pre-kernel: fused gates -> 12 U16 matrices -> f16 B-fragments in d_ws ----
__device__ __forceinline__ int fslot(int k, int n) {
    return ((k >> 3) * 16 + n) * 8 + (k & 7);
}

// One block per matrix (12 blocks): shortens the serial pre-kernel bubble.
__global__ __launch_bounds__(GBLK) void gate_kernel(
    const float* __restrict__ qw, __fp16* __restrict__ gout)
{
    __shared__ float G[NQ][8];
    const int t = threadIdx.x;
    const int mat = blockIdx.x;               // 0..11
    const int layer = mat / 3, ph = mat - 3 * layer;
    if (t < NQ) {
        const int p = layer * 3 * NQ + 3 * t;
        float t1 = qw[p], t2 = qw[p + 1], t3 = qw[p + 2];
        float a, b, c, d, gr, h;
        sincosf(0.5f * t1, &b, &a);   // RX
        sincosf(0.5f * t2, &d, &c);   // RY
        sincosf(0.5f * t3, &h, &gr);  // RZ
        float m00r =  c * a, m00i =  d * b;
        float m01r = -d * a, m01i = -c * b;
        float m10r =  d * a, m10i = -c * b;
        float m11r =  c * a, m11i = -d * b;
        float* g = G[t];
        g[0] = gr * m00r + h * m00i;  g[1] = gr * m00i - h * m00r;
        g[2] = gr * m01r + h * m01i;  g[3] = gr * m01i - h * m01r;
        g[4] = gr * m10r - h * m10i;  g[5] = gr * m10i + h * m10r;
        g[6] = gr * m11r - h * m11i;  g[7] = gr * m11i + h * m11r;
    }
    __syncthreads();
    const int n = t & 15, r = t >> 4;
    const int wbase = (ph == 0) ? 8 : (ph == 1) ? 4 : 0;
    float cr = 1.f, ci = 0.f;
    #pragma unroll
    for (int b = 0; b < 4; ++b) {         // bit (3-b) of row <-> wire wbase+b
        const float* g = G[wbase + b];
        const int rb = (r >> (3 - b)) & 1, nb = (n >> (3 - b)) & 1;
        const float er = g[(nb * 2 + rb) * 2], ei = g[(nb * 2 + rb) * 2 + 1];
        const float xr = cr * er - ci * ei, xi = cr * ei + ci * er;
        cr = xr; ci = xi;
    }
    __fp16* b1 = gout + (mat * 2 + 0) * 512;
    __fp16* b2 = gout + (mat * 2 + 1) * 512;
    b1[fslot(2 * r, n)]     = (__fp16)cr;
    b1[fslot(2 * r + 1, n)] = (__fp16)(-ci);
    b2[fslot(2 * r, n)]     = (__fp16)ci;
    b2[fslot(2 * r + 1, n)] = (__fp16)cr;
}

// q-split: wave W covers q in {2*qh, 2*qh+1} (qh = W>>2, wv = W&3).
// Same container algebra as the 4-wave version; per-wave regs halve.
#define READ_FRAGS(AF, SRC)                                                 \
    _Pragma("unroll")                                                       \
    for (int j = 0; j < 2; ++j)                                             \
        AF[j] = __builtin_bit_cast(v8h, *(const uint4*)&sh[(SRC) +          \
                    lswz((((wv) << 6) | ((2 * qh + j) << 4) | nn) * 4 + g) * 8]);

#define BLOAD(MAT)                                                          \
    const v8h b1 = gf[((MAT) * 2 + 0) * 64 + lane];                         \
    const v8h b2 = gf[((MAT) * 2 + 1) * 64 + lane];

#define MFMA_ONE(AF)                                                        \
    _Pragma("unroll")                                                       \
    for (int j = 0; j < 2; ++j) {                                           \
        d1[j] = __builtin_amdgcn_mfma_f32_16x16x32_f16(AF[j], b1, zf, 0, 0, 0); \
        d2[j] = __builtin_amdgcn_mfma_f32_16x16x32_f16(AF[j], b2, zf, 0, 0, 0); \
    }

// Keep the two samples' compute regions from being cross-pipelined
// (R2 lesson: interleaving doubles live accumulators -> VGPR cliff).
#define SCHB __builtin_amdgcn_sched_barrier(0);

#define WRITE_COLS(DST)                                                     \
    _Pragma("unroll")                                                       \
    for (int j = 0; j < 2; ++j) {                                           \
        const int CCn = (nn << 4) | (wv << 2) | (2 * qh + j);               \
        *(uint4*)&sh[(DST) + lswz(CCn * 4 + g) * 8] =                       \
            make_uint4(pk2(d1[j].x, d2[j].x), pk2(d1[j].y, d2[j].y),        \
                       pk2(d1[j].z, d2[j].z), pk2(d1[j].w, d2[j].w));       \
    }

// sq0/sq1 = sigma_inv(q<<4) pre-selected per wave (compile-time folded).
#define WRITE_SIGMA(DST)                                                    \
    _Pragma("unroll")                                                       \
    for (int j = 0; j < 2; ++j) {                                           \
        const int iq = ifix ^ (j ? sq1 : sq0);                              \
        _Pragma("unroll")                                                   \
        for (int rg = 0; rg < 4; ++rg) {                                    \
            const int ii = iq ^ sigma_inv_c(rg);                            \
            *(unsigned*)&sh[(DST) + lswz(ii >> 2) * 8 + (ii & 3) * 2] =     \
                pk2(d1[j][rg], d2[j][rg]);                                  \
        }                                                                   \
    }

// Per-sample epilogue with q-split: 8-pt WHT over (j=q0, rg); the q1=qh
// character enters as a sign; summing the two wave-halves through `red`
// reconstructs the full 16-pt WHT (the sum splits linearly over q).
// Lane-reduce only 4 stages (xor 1..8); 4 writer lanes per wave.
#define WHT_EPI(OFF)                                                        \
    { float p8[8];                                                          \
      _Pragma("unroll")                                                     \
      for (int j = 0; j < 2; ++j)                                           \
          _Pragma("unroll")                                                 \
          for (int rg = 0; rg < 4; ++rg)                                    \
              p8[j * 4 + rg] = d1[j][rg] * d1[j][rg] + d2[j][rg] * d2[j][rg]; \
      _Pragma("unroll")                                                     \
      for (int st = 1; st < 8; st <<= 1) {                                  \
          _Pragma("unroll")                                                 \
          for (int i = 0; i < 8; ++i) {                                     \
              if (!(i & st)) {                                              \
                  const float a = p8[i], b = p8[i ^ st];                    \
                  p8[i] = a + b; p8[i ^ st] = a - b;                        \
              }                                                             \
          }                                                                 \
      }                                                                     \
      float vals[NQ];                                                       \
      _Pragma("unroll")                                                     \
      for (int w = 0; w < NQ; ++w) {                                        \
          const int sb = 11 - w;                                            \
          const int f3 = (sigma_inv_c(0x20) >> sb) & 1;                     \
          const int f2 = (sigma_inv_c(0x10) >> sb) & 1;                     \
          const int f1 = (sigma_inv_c(2)    >> sb) & 1;                     \
          const int f0 = (sigma_inv_c(1)    >> sb) & 1;                     \
          const float v = p8[f2 * 4 + f1 * 2 + f0];                         \
          const int sgn = ((ifix >> sb) & 1) ^ (f3 & qh);                   \
          vals[w] = sgn ? -v : v;                                           \
      }                                                                     \
      _Pragma("unroll")                                                     \
      for (int m = 1; m <= 8; m <<= 1) {                                    \
          _Pragma("unroll")                                                 \
          for (int w = 0; w < NQ; ++w) vals[w] += __shfl_xor(vals[w], m);   \
      }                                                                     \
      if ((lane & 15) == 0) {                                               \
          _Pragma("unroll")                                                 \
          for (int w = 0; w < NQ; ++w)                                      \
              red[(OFF) + W * 48 + (lane >> 4) * 12 + w] = vals[w];         \
      } }

__global__ __launch_bounds__(QBLK) void qsim_kernel(
    const float* __restrict__ x,      // (B, 12)
    const __fp16* __restrict__ gates, // 12 x (B1,B2) f16 fragment tables (d_ws)
    const float* __restrict__ dw,     // (12, 12)
    const float* __restrict__ db,     // (12,)
    float* __restrict__ out,          // (B, 12)
    int batch)
{
    // Two samples per block (2x16KB in-place buffers), 8 waves (q-split).
    // NO min-waves rider: R1/R5 proved forced bounds always spill here.
    // Natural VGPR target <=64 -> 8 waves/SIMD -> 4 blocks/CU (128KB LDS).
    __shared__ __align__(16) __fp16 sh[16384];
    float* xv    = (float*)sh;        // [0..23]
    float* enc_c = (float*)sh + 32;   // [32..55]
    float* enc_s = (float*)sh + 64;   // [64..87]
    float* red   = (float*)sh;

    const int tid  = threadIdx.x;
    const int lane = tid & 63;
    const int W    = tid >> 6;        // wave 0..7
    const int wv   = W & 3;           // CC wave field (wires 0-1)
    const int qh   = W >> 2;          // q-half selector (q1 bit)
    const int s0   = 2 * blockIdx.x;
    int s1 = s0 + 1; if (s1 >= batch) s1 = batch - 1;   // odd-batch clamp
    const int nn = lane & 15, g = lane >> 4;
    const v8h* gf = (const v8h*)gates;
    const v4f zf = {0.f, 0.f, 0.f, 0.f};

    if (tid < 2 * NQ) {
        const int smp = tid / NQ, j = tid - smp * NQ;
        xv[tid] = x[(smp ? s1 : s0) * NQ + j];
    }
    __syncthreads();
    if (tid < 2 * NQ) {
        const int base = (tid / NQ) * NQ;
        float ss = 0.f;
        #pragma unroll
        for (int j = 0; j < NQ; ++j) ss += xv[base + j] * xv[base + j];
        float inv = rsqrtf(fmaxf(ss, 1e-12f));
        float mx = 0.f;
        #pragma unroll
        for (int j = 0; j < NQ; ++j) mx = fmaxf(mx, fabsf(xv[base + j] * inv));
        float ang = 3.14159265358979323846f * (xv[tid] * inv) / (mx + 1e-8f);
        float cc, sn;
        sincosf(0.5f * ang, &sn, &cc);
        enc_c[tid] = cc; enc_s[tid] = sn;
    }
    __syncthreads();

    // ---- product-state init as phase-A A-fragments (interleaved re/im) ----
    v8h af0[2], af1[2];
    #define PICK(SMP, WW, B) ((B) ? enc_s[(SMP) * NQ + (WW)] : enc_c[(SMP) * NQ + (WW)])
    #define INIT_AF(AF, SMP)                                                \
    {   float R4[4];                                                        \
        _Pragma("unroll")                                                   \
        for (int t = 0; t < 4; ++t) {                                       \
            const int r = 4 * g + t;                                        \
            R4[t] = PICK(SMP, 8, (r >> 3) & 1) * PICK(SMP, 9, (r >> 2) & 1) \
                  * PICK(SMP, 10, (r >> 1) & 1) * PICK(SMP, 11, r & 1);     \
        }                                                                   \
        const float Pfix = PICK(SMP, 0, (wv >> 1) & 1) * PICK(SMP, 1, wv & 1) \
                         * PICK(SMP, 4, (nn >> 3) & 1) * PICK(SMP, 5, (nn >> 2) & 1) \
                         * PICK(SMP, 6, (nn >> 1) & 1) * PICK(SMP, 7, nn & 1); \
        _Pragma("unroll")                                                   \
        for (int j = 0; j < 2; ++j) {                                       \
            const float Pq = Pfix * PICK(SMP, 2, qh) * PICK(SMP, 3, j);     \
            _Pragma("unroll")                                               \
            for (int t = 0; t < 4; ++t) {                                   \
                AF[j][2 * t]     = (__fp16)(Pq * R4[t]);                    \
                AF[j][2 * t + 1] = (__fp16)0.f;                             \
            }                                                               \
        }                                                                   \
    }
    INIT_AF(af0, 0)
    INIT_AF(af1, 1)
    #undef PICK
    __syncthreads();   // enc reads done before state buffers are written

    const int ifix = sigma_inv_c((nn << 8) | (wv << 6) | (g << 2));
    const int sq0 = qh ? sigma_inv_c(0x20) : 0;
    const int sq1 = qh ? sigma_inv_c(0x30) : sigma_inv_c(0x10);

    v4f d1[2], d2[2];
    #pragma unroll 1
    for (int l = 0; l < NL; ++l) {
        if (l > 0) {
            READ_FRAGS(af0, 0)
            READ_FRAGS(af1, S1OFF)
            __syncthreads();              // all reads landed before writes
        }
        { BLOAD(l * 3 + 0)                // wires 8..11
          MFMA_ONE(af0) WRITE_COLS(0)
          SCHB
          MFMA_ONE(af1) WRITE_COLS(S1OFF) }
        __syncthreads();

        READ_FRAGS(af0, 0)
        READ_FRAGS(af1, S1OFF)
        __syncthreads();
        { BLOAD(l * 3 + 1)                // wires 4..7
          MFMA_ONE(af0) WRITE_COLS(0)
          SCHB
          MFMA_ONE(af1) WRITE_COLS(S1OFF) }
        __syncthreads();

        READ_FRAGS(af0, 0)
        READ_FRAGS(af1, S1OFF)
        __syncthreads();                  // reads drained (sh dead if last)
        if (l < NL - 1) {
            { BLOAD(l * 3 + 2)            // wires 0..3 + CNOT ring fold
              MFMA_ONE(af0) WRITE_SIGMA(0)
              SCHB
              MFMA_ONE(af1) WRITE_SIGMA(S1OFF) }
            __syncthreads();
        } else {
            { BLOAD(l * 3 + 2)            // final: straight into epilogue
              MFMA_ONE(af0)
              WHT_EPI(0)
              SCHB
              MFMA_ONE(af1)
              WHT_EPI(384) }
        }
    }

    __syncthreads();   // all red partials written
    if (tid < 2 * NQ) {
        const int smp = tid / NQ, w = tid - smp * NQ;
        float acc = 0.f;
        #pragma unroll
        for (int k = 0; k < 32; ++k) acc += red[smp * 384 + k * 12 + w];
        red[768 + tid] = acc;
    }
    __syncthreads();
    if (tid < 2 * NQ) {
        const int smp = tid / NQ, o = tid - smp * NQ;
        const float* rv = red + 768 + smp * NQ;
        float v = db[o];
        #pragma unroll
        for (int w = 0; w < NQ; ++w) v += rv[w] * dw[w * NQ + o];
        out[(smp ? s1 : s0) * NQ + o] = tanhf(v);
    }
}

extern "C" void kernel_launch(void* const* d_in, const int* in_sizes, int n_in,
                              void* d_out, int out_size, void* d_ws, size_t ws_size,
                              hipStream_t stream) {
    const float* x  = (const float*)d_in[0];
    const float* qw = (const float*)d_in[1];
    const float* dw = (const float*)d_in[2];
    const float* db = (const float*)d_in[3];
    float* out = (float*)d_out;
    __fp16* gates = (__fp16*)d_ws;          // 12 x 2 x 512 f16 = 24576 B
    int batch = in_sizes[0] / NQ;
    int nblk = (batch + 1) / 2;
    gate_kernel<<<12, GBLK, 0, stream>>>(qw, gates);
    qsim_kernel<<<nblk, QBLK, 0, stream>>>(x, gates, dw, db, out, batch);
}

// Round 7
// 115.549 us; speedup vs baseline: 1.0708x; 1.0105x over previous
//
#include <hip/hip_runtime.h>
#include <math.h>

#define NQ   12
#define NL   4
#define GBLK 256
#define QBLK 512
#define SOFF(i) ((i) * 8192)   // per-sample state offset in __fp16 units (16 KB)

typedef float v4f  __attribute__((ext_vector_type(4)));
typedef __fp16 v8h __attribute__((ext_vector_type(8)));

// Inverse CNOT-ring map (apply CNOTs in forward order). GF(2)-linear.
__device__ __forceinline__ constexpr int sigma_inv_c(int i) {
    int j = i;
    for (int c = 0; c < NQ; ++c) {
        int t = (c + 1) % NQ;
        int cb = (j >> (NQ - 1 - c)) & 1;
        j ^= cb << (NQ - 1 - t);
    }
    return j;
}

// State buffer: amp (col CC(8b), row r(4b)) as interleaved (re,im) f16 pair.
// 16B line = 4 amps: line = CC*4 + (r>>2). Line swizzle keeps both the
// fragment reads and column writes <=2-way bank conflicts.
__device__ __forceinline__ constexpr int lswz(int l) {
    return l ^ (((l >> 3) ^ (l >> 7)) & 7);
}

__device__ __forceinline__ unsigned pk2(float a, float b) {
    return __builtin_bit_cast(unsigned, __builtin_amdgcn_cvt_pkrtz(a, b));
}

// ---- pre-kernel: fused gates -> 12 U16 matrices -> f16 B-fragments in d_ws ----
__device__ __forceinline__ int fslot(int k, int n) {
    return ((k >> 3) * 16 + n) * 8 + (k & 7);
}

// One block per matrix (12 blocks): shortens the serial pre-kernel bubble.
__global__ __launch_bounds__(GBLK) void gate_kernel(
    const float* __restrict__ qw, __fp16* __restrict__ gout)
{
    __shared__ float G[NQ][8];
    const int t = threadIdx.x;
    const int mat = blockIdx.x;               // 0..11
    const int layer = mat / 3, ph = mat - 3 * layer;
    if (t < NQ) {
        const int p = layer * 3 * NQ + 3 * t;
        float t1 = qw[p], t2 = qw[p + 1], t3 = qw[p + 2];
        float a, b, c, d, gr, h;
        sincosf(0.5f * t1, &b, &a);   // RX
        sincosf(0.5f * t2, &d, &c);   // RY
        sincosf(0.5f * t3, &h, &gr);  // RZ
        float m00r =  c * a, m00i =  d * b;
        float m01r = -d * a, m01i = -c * b;
        float m10r =  d * a, m10i = -c * b;
        float m11r =  c * a, m11i = -d * b;
        float* g = G[t];
        g[0] = gr * m00r + h * m00i;  g[1] = gr * m00i - h * m00r;
        g[2] = gr * m01r + h * m01i;  g[3] = gr * m01i - h * m01r;
        g[4] = gr * m10r - h * m10i;  g[5] = gr * m10i + h * m10r;
        g[6] = gr * m11r - h * m11i;  g[7] = gr * m11i + h * m11r;
    }
    __syncthreads();
    const int n = t & 15, r = t >> 4;
    const int wbase = (ph == 0) ? 8 : (ph == 1) ? 4 : 0;
    float cr = 1.f, ci = 0.f;
    #pragma unroll
    for (int b = 0; b < 4; ++b) {         // bit (3-b) of row <-> wire wbase+b
        const float* g = G[wbase + b];
        const int rb = (r >> (3 - b)) & 1, nb = (n >> (3 - b)) & 1;
        const float er = g[(nb * 2 + rb) * 2], ei = g[(nb * 2 + rb) * 2 + 1];
        const float xr = cr * er - ci * ei, xi = cr * ei + ci * er;
        cr = xr; ci = xi;
    }
    __fp16* b1 = gout + (mat * 2 + 0) * 512;
    __fp16* b2 = gout + (mat * 2 + 1) * 512;
    b1[fslot(2 * r, n)]     = (__fp16)cr;
    b1[fslot(2 * r + 1, n)] = (__fp16)(-ci);
    b2[fslot(2 * r, n)]     = (__fp16)ci;
    b2[fslot(2 * r + 1, n)] = (__fp16)cr;
}

// q-split: wave W covers q in {2*qh, 2*qh+1} (qh = W>>2, wv = W&3).
#define READ_FRAGS(AF, SRC)                                                 \
    _Pragma("unroll")                                                       \
    for (int j = 0; j < 2; ++j)                                             \
        AF[j] = __builtin_bit_cast(v8h, *(const uint4*)&sh[(SRC) +          \
                    lswz((((wv) << 6) | ((2 * qh + j) << 4) | nn) * 4 + g) * 8]);

#define BLOAD(MAT)                                                          \
    const v8h b1 = gf[((MAT) * 2 + 0) * 64 + lane];                         \
    const v8h b2 = gf[((MAT) * 2 + 1) * 64 + lane];

#define MFMA_ONE(AF)                                                        \
    _Pragma("unroll")                                                       \
    for (int j = 0; j < 2; ++j) {                                           \
        d1[j] = __builtin_amdgcn_mfma_f32_16x16x32_f16(AF[j], b1, zf, 0, 0, 0); \
        d2[j] = __builtin_amdgcn_mfma_f32_16x16x32_f16(AF[j], b2, zf, 0, 0, 0); \
    }

// Keep per-sample compute regions from being cross-pipelined
// (R2 lesson: interleaving multiplies live accumulators -> VGPR cliff).
#define SCHB __builtin_amdgcn_sched_barrier(0);

#define WRITE_COLS(DST)                                                     \
    _Pragma("unroll")                                                       \
    for (int j = 0; j < 2; ++j) {                                           \
        const int CCn = (nn << 4) | (wv << 2) | (2 * qh + j);               \
        *(uint4*)&sh[(DST) + lswz(CCn * 4 + g) * 8] =                       \
            make_uint4(pk2(d1[j].x, d2[j].x), pk2(d1[j].y, d2[j].y),        \
                       pk2(d1[j].z, d2[j].z), pk2(d1[j].w, d2[j].w));       \
    }

// sq0/sq1 = sigma_inv(q<<4) pre-selected per wave (compile-time folded).
#define WRITE_SIGMA(DST)                                                    \
    _Pragma("unroll")                                                       \
    for (int j = 0; j < 2; ++j) {                                           \
        const int iq = ifix ^ (j ? sq1 : sq0);                              \
        _Pragma("unroll")                                                   \
        for (int rg = 0; rg < 4; ++rg) {                                    \
            const int ii = iq ^ sigma_inv_c(rg);                            \
            *(unsigned*)&sh[(DST) + lswz(ii >> 2) * 8 + (ii & 3) * 2] =     \
                pk2(d1[j][rg], d2[j][rg]);                                  \
        }                                                                   \
    }

// Per-sample epilogue with q-split: 8-pt WHT over (j=q0, rg); qh enters as
// a sign; summing wave-halves through `red` rebuilds the 16-pt WHT.
#define WHT_EPI(OFF)                                                        \
    { float p8[8];                                                          \
      _Pragma("unroll")                                                     \
      for (int j = 0; j < 2; ++j)                                           \
          _Pragma("unroll")                                                 \
          for (int rg = 0; rg < 4; ++rg)                                    \
              p8[j * 4 + rg] = d1[j][rg] * d1[j][rg] + d2[j][rg] * d2[j][rg]; \
      _Pragma("unroll")                                                     \
      for (int st = 1; st < 8; st <<= 1) {                                  \
          _Pragma("unroll")                                                 \
          for (int i = 0; i < 8; ++i) {                                     \
              if (!(i & st)) {                                              \
                  const float a = p8[i], b = p8[i ^ st];                    \
                  p8[i] = a + b; p8[i ^ st] = a - b;                        \
              }                                                             \
          }                                                                 \
      }                                                                     \
      float vals[NQ];                                                       \
      _Pragma("unroll")                                                     \
      for (int w = 0; w < NQ; ++w) {                                        \
          const int sb = 11 - w;                                            \
          const int f3 = (sigma_inv_c(0x20) >> sb) & 1;                     \
          const int f2 = (sigma_inv_c(0x10) >> sb) & 1;                     \
          const int f1 = (sigma_inv_c(2)    >> sb) & 1;                     \
          const int f0 = (sigma_inv_c(1)    >> sb) & 1;                     \
          const float v = p8[f2 * 4 + f1 * 2 + f0];                         \
          const int sgn = ((ifix >> sb) & 1) ^ (f3 & qh);                   \
          vals[w] = sgn ? -v : v;                                           \
      }                                                                     \
      _Pragma("unroll")                                                     \
      for (int m = 1; m <= 8; m <<= 1) {                                    \
          _Pragma("unroll")                                                 \
          for (int w = 0; w < NQ; ++w) vals[w] += __shfl_xor(vals[w], m);   \
      }                                                                     \
      if ((lane & 15) == 0) {                                               \
          _Pragma("unroll")                                                 \
          for (int w = 0; w < NQ; ++w)                                      \
              red[(OFF) + W * 48 + (lane >> 4) * 12 + w] = vals[w];         \
      } }

__global__ __launch_bounds__(QBLK) void qsim_kernel(
    const float* __restrict__ x,      // (B, 12)
    const __fp16* __restrict__ gates, // 12 x (B1,B2) f16 fragment tables (d_ws)
    const float* __restrict__ dw,     // (12, 12)
    const float* __restrict__ db,     // (12,)
    float* __restrict__ out,          // (B, 12)
    int batch)
{
    // FOUR samples per block (4x16KB in-place buffers), 8 waves (q-split).
    // 64KB LDS -> 2 blocks/CU; amortizes barrier drains, B-loads, and
    // encode/epilogue over 4 samples. NO min-waves rider (R1/R5: spills).
    __shared__ __align__(16) __fp16 sh[32768];
    float* xv    = (float*)sh;        // [0..47]
    float* enc_c = (float*)sh + 64;   // [64..111]
    float* enc_s = (float*)sh + 128;  // [128..175]
    float* red   = (float*)sh;

    const int tid  = threadIdx.x;
    const int lane = tid & 63;
    const int W    = tid >> 6;        // wave 0..7
    const int wv   = W & 3;           // CC wave field (wires 0-1)
    const int qh   = W >> 2;          // q-half selector (q1 bit)
    const int base = 4 * blockIdx.x;
    int ss[4];
    #pragma unroll
    for (int i = 0; i < 4; ++i) {
        int s = base + i;
        ss[i] = (s < batch) ? s : batch - 1;   // tail clamp (dup writes benign)
    }
    const int nn = lane & 15, g = lane >> 4;
    const v8h* gf = (const v8h*)gates;
    const v4f zf = {0.f, 0.f, 0.f, 0.f};

    if (tid < 4 * NQ) {
        const int smp = tid / NQ, j = tid - smp * NQ;
        xv[tid] = x[ss[smp] * NQ + j];
    }
    __syncthreads();
    if (tid < 4 * NQ) {
        const int b0 = (tid / NQ) * NQ;
        float sum = 0.f;
        #pragma unroll
        for (int j = 0; j < NQ; ++j) sum += xv[b0 + j] * xv[b0 + j];
        float inv = rsqrtf(fmaxf(sum, 1e-12f));
        float mx = 0.f;
        #pragma unroll
        for (int j = 0; j < NQ; ++j) mx = fmaxf(mx, fabsf(xv[b0 + j] * inv));
        float ang = 3.14159265358979323846f * (xv[tid] * inv) / (mx + 1e-8f);
        float cc, sn;
        sincosf(0.5f * ang, &sn, &cc);
        enc_c[tid] = cc; enc_s[tid] = sn;
    }
    __syncthreads();

    // ---- product-state init as phase-A A-fragments (interleaved re/im) ----
    v8h af0[2], af1[2], af2[2], af3[2];
    #define PICK(SMP, WW, B) ((B) ? enc_s[(SMP) * NQ + (WW)] : enc_c[(SMP) * NQ + (WW)])
    #define INIT_AF(AF, SMP)                                                \
    {   float R4[4];                                                        \
        _Pragma("unroll")                                                   \
        for (int t = 0; t < 4; ++t) {                                       \
            const int r = 4 * g + t;                                        \
            R4[t] = PICK(SMP, 8, (r >> 3) & 1) * PICK(SMP, 9, (r >> 2) & 1) \
                  * PICK(SMP, 10, (r >> 1) & 1) * PICK(SMP, 11, r & 1);     \
        }                                                                   \
        const float Pfix = PICK(SMP, 0, (wv >> 1) & 1) * PICK(SMP, 1, wv & 1) \
                         * PICK(SMP, 4, (nn >> 3) & 1) * PICK(SMP, 5, (nn >> 2) & 1) \
                         * PICK(SMP, 6, (nn >> 1) & 1) * PICK(SMP, 7, nn & 1); \
        _Pragma("unroll")                                                   \
        for (int j = 0; j < 2; ++j) {                                       \
            const float Pq = Pfix * PICK(SMP, 2, qh) * PICK(SMP, 3, j);     \
            _Pragma("unroll")                                               \
            for (int t = 0; t < 4; ++t) {                                   \
                AF[j][2 * t]     = (__fp16)(Pq * R4[t]);                    \
                AF[j][2 * t + 1] = (__fp16)0.f;                             \
            }                                                               \
        }                                                                   \
    }
    INIT_AF(af0, 0)
    INIT_AF(af1, 1)
    INIT_AF(af2, 2)
    INIT_AF(af3, 3)
    #undef PICK
    __syncthreads();   // enc reads done before state buffers are written

    const int ifix = sigma_inv_c((nn << 8) | (wv << 6) | (g << 2));
    const int sq0 = qh ? sigma_inv_c(0x20) : 0;
    const int sq1 = qh ? sigma_inv_c(0x30) : sigma_inv_c(0x10);

    v4f d1[2], d2[2];
    #define READ4                                                           \
        READ_FRAGS(af0, SOFF(0)) READ_FRAGS(af1, SOFF(1))                   \
        READ_FRAGS(af2, SOFF(2)) READ_FRAGS(af3, SOFF(3))
    #define COLS4(MAT)                                                      \
        { BLOAD(MAT)                                                        \
          MFMA_ONE(af0) WRITE_COLS(SOFF(0)) SCHB                            \
          MFMA_ONE(af1) WRITE_COLS(SOFF(1)) SCHB                            \
          MFMA_ONE(af2) WRITE_COLS(SOFF(2)) SCHB                            \
          MFMA_ONE(af3) WRITE_COLS(SOFF(3)) }
    #define SIGMA4(MAT)                                                     \
        { BLOAD(MAT)                                                        \
          MFMA_ONE(af0) WRITE_SIGMA(SOFF(0)) SCHB                           \
          MFMA_ONE(af1) WRITE_SIGMA(SOFF(1)) SCHB                           \
          MFMA_ONE(af2) WRITE_SIGMA(SOFF(2)) SCHB                           \
          MFMA_ONE(af3) WRITE_SIGMA(SOFF(3)) }

    #pragma unroll 1
    for (int l = 0; l < NL; ++l) {
        if (l > 0) {
            READ4
            __syncthreads();              // all reads landed before writes
        }
        COLS4(l * 3 + 0)                  // wires 8..11
        __syncthreads();

        READ4
        __syncthreads();
        COLS4(l * 3 + 1)                  // wires 4..7
        __syncthreads();

        READ4
        __syncthreads();                  // reads drained (sh dead if last)
        if (l < NL - 1) {
            SIGMA4(l * 3 + 2)             // wires 0..3 + CNOT ring fold
            __syncthreads();
        } else {
            { BLOAD(l * 3 + 2)            // final: straight into epilogue
              MFMA_ONE(af0) WHT_EPI(0)    SCHB
              MFMA_ONE(af1) WHT_EPI(384)  SCHB
              MFMA_ONE(af2) WHT_EPI(768)  SCHB
              MFMA_ONE(af3) WHT_EPI(1152) }
        }
    }

    __syncthreads();   // all red partials written
    if (tid < 4 * NQ) {
        const int smp = tid / NQ, w = tid - smp * NQ;
        float acc = 0.f;
        #pragma unroll
        for (int k = 0; k < 32; ++k) acc += red[smp * 384 + k * 12 + w];
        red[1536 + tid] = acc;
    }
    __syncthreads();
    if (tid < 4 * NQ) {
        const int smp = tid / NQ, o = tid - smp * NQ;
        const float* rv = red + 1536 + smp * NQ;
        float v = db[o];
        #pragma unroll
        for (int w = 0; w < NQ; ++w) v += rv[w] * dw[w * NQ + o];
        out[ss[smp] * NQ + o] = tanhf(v);
    }
}

extern "C" void kernel_launch(void* const* d_in, const int* in_sizes, int n_in,
                              void* d_out, int out_size, void* d_ws, size_t ws_size,
                              hipStream_t stream) {
    const float* x  = (const float*)d_in[0];
    const float* qw = (const float*)d_in[1];
    const float* dw = (const float*)d_in[2];
    const float* db = (const float*)d_in[3];
    float* out = (float*)d_out;
    __fp16* gates = (__fp16*)d_ws;          // 12 x 2 x 512 f16 = 24576 B
    int batch = in_sizes[0] / NQ;
    int nblk = (batch + 3) / 4;
    gate_kernel<<<12, GBLK, 0, stream>>>(qw, gates);
    qsim_kernel<<<nblk, QBLK, 0, stream>>>(x, gates, dw, db, out, batch);
}

// Round 8
// 107.908 us; speedup vs baseline: 1.1466x; 1.0708x over previous
//
#include <hip/hip_runtime.h>
#include <math.h>

#define NQ   12
#define NL   4
#define GBLK 256
#define QBLK 512
#define SOFF(i) ((i) * 8192)   // per-sample state offset in __fp16 units (16 KB)

typedef float v4f  __attribute__((ext_vector_type(4)));
typedef __fp16 v8h __attribute__((ext_vector_type(8)));
typedef unsigned v4u __attribute__((ext_vector_type(4)));

// Inverse CNOT-ring map (apply CNOTs in forward order). GF(2)-linear.
__device__ __forceinline__ constexpr int sigma_inv_c(int i) {
    int j = i;
    for (int c = 0; c < NQ; ++c) {
        int t = (c + 1) % NQ;
        int cb = (j >> (NQ - 1 - c)) & 1;
        j ^= cb << (NQ - 1 - t);
    }
    return j;
}

// State buffer: amp (col CC(8b), row r(4b)) as interleaved (re,im) f16 pair.
// 16B line = 4 amps: line = CC*4 + (r>>2). Line swizzle keeps both the
// fragment reads and column writes <=2-way bank conflicts.
__device__ __forceinline__ constexpr int lswz(int l) {
    return l ^ (((l >> 3) ^ (l >> 7)) & 7);
}

__device__ __forceinline__ unsigned pk2(float a, float b) {
    return __builtin_bit_cast(unsigned, __builtin_amdgcn_cvt_pkrtz(a, b));
}

// ---- pre-kernel: fused gates -> 12 U16 matrices -> f16 B-fragments in d_ws ----
__device__ __forceinline__ int fslot(int k, int n) {
    return ((k >> 3) * 16 + n) * 8 + (k & 7);
}

// One block per matrix (12 blocks): shortens the serial pre-kernel bubble.
__global__ __launch_bounds__(GBLK) void gate_kernel(
    const float* __restrict__ qw, __fp16* __restrict__ gout)
{
    __shared__ float G[NQ][8];
    const int t = threadIdx.x;
    const int mat = blockIdx.x;               // 0..11
    const int layer = mat / 3, ph = mat - 3 * layer;
    if (t < NQ) {
        const int p = layer * 3 * NQ + 3 * t;
        float t1 = qw[p], t2 = qw[p + 1], t3 = qw[p + 2];
        float a, b, c, d, gr, h;
        sincosf(0.5f * t1, &b, &a);   // RX
        sincosf(0.5f * t2, &d, &c);   // RY
        sincosf(0.5f * t3, &h, &gr);  // RZ
        float m00r =  c * a, m00i =  d * b;
        float m01r = -d * a, m01i = -c * b;
        float m10r =  d * a, m10i = -c * b;
        float m11r =  c * a, m11i = -d * b;
        float* g = G[t];
        g[0] = gr * m00r + h * m00i;  g[1] = gr * m00i - h * m00r;
        g[2] = gr * m01r + h * m01i;  g[3] = gr * m01i - h * m01r;
        g[4] = gr * m10r - h * m10i;  g[5] = gr * m10i + h * m10r;
        g[6] = gr * m11r - h * m11i;  g[7] = gr * m11i + h * m11r;
    }
    __syncthreads();
    const int n = t & 15, r = t >> 4;
    const int wbase = (ph == 0) ? 8 : (ph == 1) ? 4 : 0;
    float cr = 1.f, ci = 0.f;
    #pragma unroll
    for (int b = 0; b < 4; ++b) {         // bit (3-b) of row <-> wire wbase+b
        const float* g = G[wbase + b];
        const int rb = (r >> (3 - b)) & 1, nb = (n >> (3 - b)) & 1;
        const float er = g[(nb * 2 + rb) * 2], ei = g[(nb * 2 + rb) * 2 + 1];
        const float xr = cr * er - ci * ei, xi = cr * ei + ci * er;
        cr = xr; ci = xi;
    }
    __fp16* b1 = gout + (mat * 2 + 0) * 512;
    __fp16* b2 = gout + (mat * 2 + 1) * 512;
    b1[fslot(2 * r, n)]     = (__fp16)cr;
    b1[fslot(2 * r + 1, n)] = (__fp16)(-ci);
    b2[fslot(2 * r, n)]     = (__fp16)ci;
    b2[fslot(2 * r + 1, n)] = (__fp16)cr;
}

// q-split: wave W covers q in {2*qh, 2*qh+1} (qh = W>>2, wv = W&3).
#define READ_FRAGS(AF, SRC)                                                 \
    _Pragma("unroll")                                                       \
    for (int j = 0; j < 2; ++j)                                             \
        AF[j] = __builtin_bit_cast(v8h, *(const uint4*)&sh[(SRC) +          \
                    lswz((((wv) << 6) | ((2 * qh + j) << 4) | nn) * 4 + g) * 8]);

#define BLOAD(MAT)                                                          \
    const v8h b1 = gf[((MAT) * 2 + 0) * 64 + lane];                         \
    const v8h b2 = gf[((MAT) * 2 + 1) * 64 + lane];

// B and C gate tables co-resident for the chained phase pair.
#define BLOAD2(MATB, MATC)                                                  \
    const v8h b1 = gf[((MATB) * 2 + 0) * 64 + lane];                        \
    const v8h b2 = gf[((MATB) * 2 + 1) * 64 + lane];                        \
    const v8h c1 = gf[((MATC) * 2 + 0) * 64 + lane];                        \
    const v8h c2 = gf[((MATC) * 2 + 1) * 64 + lane];

#define MFMA_ONE(AF)                                                        \
    _Pragma("unroll")                                                       \
    for (int j = 0; j < 2; ++j) {                                           \
        d1[j] = __builtin_amdgcn_mfma_f32_16x16x32_f16(AF[j], b1, zf, 0, 0, 0); \
        d2[j] = __builtin_amdgcn_mfma_f32_16x16x32_f16(AF[j], b2, zf, 0, 0, 0); \
    }

// In-register B->C chain: phase-B's D output at lane L (rows 4g+rg = w0-3
// values, col L&15 = w4-7') IS the phase-C A-fragment layout: element
// (2rg, 2rg+1) = (re, im) = pk2(d1[rg], d2[rg]). No LDS, no shuffles.
#define PACK_AF(AF)                                                         \
    _Pragma("unroll")                                                       \
    for (int j = 0; j < 2; ++j) {                                           \
        v4u t;                                                              \
        _Pragma("unroll")                                                   \
        for (int rg = 0; rg < 4; ++rg) t[rg] = pk2(d1[j][rg], d2[j][rg]);   \
        AF[j] = __builtin_bit_cast(v8h, t);                                 \
    }

#define MFMA_CC(AF)                                                         \
    _Pragma("unroll")                                                       \
    for (int j = 0; j < 2; ++j) {                                           \
        d1[j] = __builtin_amdgcn_mfma_f32_16x16x32_f16(AF[j], c1, zf, 0, 0, 0); \
        d2[j] = __builtin_amdgcn_mfma_f32_16x16x32_f16(AF[j], c2, zf, 0, 0, 0); \
    }

// Keep per-sample compute regions from being cross-pipelined
// (R2 lesson: interleaving multiplies live accumulators -> VGPR cliff).
#define SCHB __builtin_amdgcn_sched_barrier(0);

#define WRITE_COLS(DST)                                                     \
    _Pragma("unroll")                                                       \
    for (int j = 0; j < 2; ++j) {                                           \
        const int CCn = (nn << 4) | (wv << 2) | (2 * qh + j);               \
        *(uint4*)&sh[(DST) + lswz(CCn * 4 + g) * 8] =                       \
            make_uint4(pk2(d1[j].x, d2[j].x), pk2(d1[j].y, d2[j].y),        \
                       pk2(d1[j].z, d2[j].z), pk2(d1[j].w, d2[j].w));       \
    }

// Sigma scatter from chained-C output. Element (j,rg) has pre-CNOT index
// pre_idx = (nn<<8)|((4g+rg)<<4)|(wv<<2)|(qh<<1)|j; slot = sigma_inv(pre_idx)
// = ifix2 ^ sigma_inv(rg<<4) ^ (j ? sigma_inv(1) : 0)  (GF(2)-linear).
#define WRITE_SIGMA2(DST)                                                   \
    _Pragma("unroll")                                                       \
    for (int j = 0; j < 2; ++j) {                                           \
        const int ij = ifix2 ^ (j ? sigma_inv_c(1) : 0);                    \
        _Pragma("unroll")                                                   \
        for (int rg = 0; rg < 4; ++rg) {                                    \
            const int ii = ij ^ sigma_inv_c(rg << 4);                       \
            *(unsigned*)&sh[(DST) + lswz(ii >> 2) * 8 + (ii & 3) * 2] =     \
                pk2(d1[j][rg], d2[j][rg]);                                  \
        }                                                                   \
    }

// Epilogue from chained-C output: 8-pt WHT over (j at bit2, rg at bits 1:0);
// characters at generators {0x01 (j), 0x20 (rg hi), 0x10 (rg lo)}; sign fix
// from ifix2. Shuffle-reduce 16 lanes; 4 writer lanes per wave.
#define WHT_EPI2(OFF)                                                       \
    { float p8[8];                                                          \
      _Pragma("unroll")                                                     \
      for (int j = 0; j < 2; ++j)                                           \
          _Pragma("unroll")                                                 \
          for (int rg = 0; rg < 4; ++rg)                                    \
              p8[j * 4 + rg] = d1[j][rg] * d1[j][rg] + d2[j][rg] * d2[j][rg]; \
      _Pragma("unroll")                                                     \
      for (int st = 1; st < 8; st <<= 1) {                                  \
          _Pragma("unroll")                                                 \
          for (int i = 0; i < 8; ++i) {                                     \
              if (!(i & st)) {                                              \
                  const float a = p8[i], b = p8[i ^ st];                    \
                  p8[i] = a + b; p8[i ^ st] = a - b;                        \
              }                                                             \
          }                                                                 \
      }                                                                     \
      float vals[NQ];                                                       \
      _Pragma("unroll")                                                     \
      for (int w = 0; w < NQ; ++w) {                                        \
          const int sb = 11 - w;                                            \
          const int fj  = (sigma_inv_c(0x001) >> sb) & 1;                   \
          const int frh = (sigma_inv_c(0x020) >> sb) & 1;                   \
          const int frl = (sigma_inv_c(0x010) >> sb) & 1;                   \
          const float v = p8[fj * 4 + frh * 2 + frl];                       \
          vals[w] = ((ifix2 >> sb) & 1) ? -v : v;                           \
      }                                                                     \
      _Pragma("unroll")                                                     \
      for (int m = 1; m <= 8; m <<= 1) {                                    \
          _Pragma("unroll")                                                 \
          for (int w = 0; w < NQ; ++w) vals[w] += __shfl_xor(vals[w], m);   \
      }                                                                     \
      if ((lane & 15) == 0) {                                               \
          _Pragma("unroll")                                                 \
          for (int w = 0; w < NQ; ++w)                                      \
              red[(OFF) + W * 48 + (lane >> 4) * 12 + w] = vals[w];         \
      } }

__global__ __launch_bounds__(QBLK) void qsim_kernel(
    const float* __restrict__ x,      // (B, 12)
    const __fp16* __restrict__ gates, // 12 x (B1,B2) f16 fragment tables (d_ws)
    const float* __restrict__ dw,     // (12, 12)
    const float* __restrict__ db,     // (12,)
    float* __restrict__ out,          // (B, 12)
    int batch)
{
    // FOUR samples per block (4x16KB in-place buffers), 8 waves (q-split).
    // Per layer: [read A | MFMA_A + cols-write | read B | MFMA_B ->reg pack->
    // MFMA_C + sigma-scatter]: B's write and C's read are eliminated
    // (in-register chain) -> LDS ops -29%, barrier regions 23 -> 14.
    __shared__ __align__(16) __fp16 sh[32768];
    float* xv    = (float*)sh;        // [0..47]
    float* enc_c = (float*)sh + 64;   // [64..111]
    float* enc_s = (float*)sh + 128;  // [128..175]
    float* red   = (float*)sh;

    const int tid  = threadIdx.x;
    const int lane = tid & 63;
    const int W    = tid >> 6;        // wave 0..7
    const int wv   = W & 3;           // CC wave field
    const int qh   = W >> 2;          // q-half selector
    const int base = 4 * blockIdx.x;
    int ss[4];
    #pragma unroll
    for (int i = 0; i < 4; ++i) {
        int s = base + i;
        ss[i] = (s < batch) ? s : batch - 1;   // tail clamp (dup writes benign)
    }
    const int nn = lane & 15, g = lane >> 4;
    const v8h* gf = (const v8h*)gates;
    const v4f zf = {0.f, 0.f, 0.f, 0.f};

    if (tid < 4 * NQ) {
        const int smp = tid / NQ, j = tid - smp * NQ;
        xv[tid] = x[ss[smp] * NQ + j];
    }
    __syncthreads();
    if (tid < 4 * NQ) {
        const int b0 = (tid / NQ) * NQ;
        float sum = 0.f;
        #pragma unroll
        for (int j = 0; j < NQ; ++j) sum += xv[b0 + j] * xv[b0 + j];
        float inv = rsqrtf(fmaxf(sum, 1e-12f));
        float mx = 0.f;
        #pragma unroll
        for (int j = 0; j < NQ; ++j) mx = fmaxf(mx, fabsf(xv[b0 + j] * inv));
        float ang = 3.14159265358979323846f * (xv[tid] * inv) / (mx + 1e-8f);
        float cc, sn;
        sincosf(0.5f * ang, &sn, &cc);
        enc_c[tid] = cc; enc_s[tid] = sn;
    }
    __syncthreads();

    // ---- product-state init as phase-A A-fragments (interleaved re/im) ----
    v8h af0[2], af1[2], af2[2], af3[2];
    #define PICK(SMP, WW, B) ((B) ? enc_s[(SMP) * NQ + (WW)] : enc_c[(SMP) * NQ + (WW)])
    #define INIT_AF(AF, SMP)                                                \
    {   float R4[4];                                                        \
        _Pragma("unroll")                                                   \
        for (int t = 0; t < 4; ++t) {                                       \
            const int r = 4 * g + t;                                        \
            R4[t] = PICK(SMP, 8, (r >> 3) & 1) * PICK(SMP, 9, (r >> 2) & 1) \
                  * PICK(SMP, 10, (r >> 1) & 1) * PICK(SMP, 11, r & 1);     \
        }                                                                   \
        const float Pfix = PICK(SMP, 0, (wv >> 1) & 1) * PICK(SMP, 1, wv & 1) \
                         * PICK(SMP, 4, (nn >> 3) & 1) * PICK(SMP, 5, (nn >> 2) & 1) \
                         * PICK(SMP, 6, (nn >> 1) & 1) * PICK(SMP, 7, nn & 1); \
        _Pragma("unroll")                                                   \
        for (int j = 0; j < 2; ++j) {                                       \
            const float Pq = Pfix * PICK(SMP, 2, qh) * PICK(SMP, 3, j);     \
            _Pragma("unroll")                                               \
            for (int t = 0; t < 4; ++t) {                                   \
                AF[j][2 * t]     = (__fp16)(Pq * R4[t]);                    \
                AF[j][2 * t + 1] = (__fp16)0.f;                             \
            }                                                               \
        }                                                                   \
    }
    INIT_AF(af0, 0)
    INIT_AF(af1, 1)
    INIT_AF(af2, 2)
    INIT_AF(af3, 3)
    #undef PICK
    __syncthreads();   // enc reads done before state buffers are written

    // Loop-invariant sigma constant for the chained-C output index map.
    const int ifix2 = sigma_inv_c((nn << 8) | (g << 6) | (wv << 2) | (qh << 1));

    v4f d1[2], d2[2];
    #define READ4                                                           \
        READ_FRAGS(af0, SOFF(0)) READ_FRAGS(af1, SOFF(1))                   \
        READ_FRAGS(af2, SOFF(2)) READ_FRAGS(af3, SOFF(3))
    #define COLS4(MAT)                                                      \
        { BLOAD(MAT)                                                        \
          MFMA_ONE(af0) WRITE_COLS(SOFF(0)) SCHB                            \
          MFMA_ONE(af1) WRITE_COLS(SOFF(1)) SCHB                            \
          MFMA_ONE(af2) WRITE_COLS(SOFF(2)) SCHB                            \
          MFMA_ONE(af3) WRITE_COLS(SOFF(3)) }
    // Chained B->C with sigma scatter (mid layers).
    #define CHAIN_S(AF, DST)                                                \
        MFMA_ONE(AF) PACK_AF(AF) MFMA_CC(AF) WRITE_SIGMA2(DST)
    // Chained B->C straight into epilogue (last layer).
    #define CHAIN_E(AF, EOFF)                                               \
        MFMA_ONE(AF) PACK_AF(AF) MFMA_CC(AF) WHT_EPI2(EOFF)

    #pragma unroll 1
    for (int l = 0; l < NL; ++l) {
        if (l > 0) {
            READ4
            __syncthreads();              // all reads landed before writes
        }
        COLS4(l * 3 + 0)                  // phase A: wires 8..11
        __syncthreads();

        READ4
        __syncthreads();                  // reads drained (sh dead if last)
        if (l < NL - 1) {
            { BLOAD2(l * 3 + 1, l * 3 + 2)
              CHAIN_S(af0, SOFF(0)) SCHB
              CHAIN_S(af1, SOFF(1)) SCHB
              CHAIN_S(af2, SOFF(2)) SCHB
              CHAIN_S(af3, SOFF(3)) }
            __syncthreads();
        } else {
            { BLOAD2(l * 3 + 1, l * 3 + 2)
              CHAIN_E(af0, 0)    SCHB
              CHAIN_E(af1, 384)  SCHB
              CHAIN_E(af2, 768)  SCHB
              CHAIN_E(af3, 1152) }
        }
    }

    __syncthreads();   // all red partials written
    if (tid < 4 * NQ) {
        const int smp = tid / NQ, w = tid - smp * NQ;
        float acc = 0.f;
        #pragma unroll
        for (int k = 0; k < 32; ++k) acc += red[smp * 384 + k * 12 + w];
        red[1536 + tid] = acc;
    }
    __syncthreads();
    if (tid < 4 * NQ) {
        const int smp = tid / NQ, o = tid - smp * NQ;
        const float* rv = red + 1536 + smp * NQ;
        float v = db[o];
        #pragma unroll
        for (int w = 0; w < NQ; ++w) v += rv[w] * dw[w * NQ + o];
        out[ss[smp] * NQ + o] = tanhf(v);
    }
}

extern "C" void kernel_launch(void* const* d_in, const int* in_sizes, int n_in,
                              void* d_out, int out_size, void* d_ws, size_t ws_size,
                              hipStream_t stream) {
    const float* x  = (const float*)d_in[0];
    const float* qw = (const float*)d_in[1];
    const float* dw = (const float*)d_in[2];
    const float* db = (const float*)d_in[3];
    float* out = (float*)d_out;
    __fp16* gates = (__fp16*)d_ws;          // 12 x 2 x 512 f16 = 24576 B
    int batch = in_sizes[0] / NQ;
    int nblk = (batch + 3) / 4;
    gate_kernel<<<12, GBLK, 0, stream>>>(qw, gates);
    qsim_kernel<<<nblk, QBLK, 0, stream>>>(x, gates, dw, db, out, batch);
}